// Round 1
// baseline (1633.432 us; speedup 1.0000x reference)
//
#include <hip/hip_runtime.h>

#define N_NODES 40000
#define N_EDGES 400000
#define N_GRAPHS 64
#define D1 256      // heads*hid for conv1
#define HIDC 64
#define NHEADS 4
#define EDIM 18
#define OUTF 3

#define ENC_NEG_INF 0x007FFFFFu

__device__ __forceinline__ unsigned int enc_f(float f) {
    unsigned int b = __float_as_uint(f);
    return (b & 0x80000000u) ? ~b : (b | 0x80000000u);
}
__device__ __forceinline__ float dec_f(unsigned int u) {
    unsigned int b = (u & 0x80000000u) ? (u ^ 0x80000000u) : ~u;
    return __uint_as_float(b);
}

__device__ __forceinline__ float wave_reduce_sum(float v) {
    #pragma unroll
    for (int off = 32; off > 0; off >>= 1) v += __shfl_down(v, off);
    return v;  // valid in lane 0 of the wave
}

// ---------------- init ----------------
__global__ void init1_kernel(float* __restrict__ out1, float* __restrict__ den1,
                             unsigned int* __restrict__ amax1) {
    int tid = blockIdx.x * 256 + threadIdx.x;   // N*256 threads
    out1[tid] = 0.f;
    if (tid < N_NODES * NHEADS) { den1[tid] = 0.f; amax1[tid] = ENC_NEG_INF; }
}

__global__ void init2_kernel(float* __restrict__ out2, float* __restrict__ den2,
                             unsigned int* __restrict__ amax2,
                             float* __restrict__ pooled, float* __restrict__ cnt) {
    int tid = blockIdx.x * 256 + threadIdx.x;   // N*64 threads
    out2[tid] = 0.f;
    if (tid < N_NODES) { den2[tid] = 0.f; amax2[tid] = ENC_NEG_INF; }
    if (tid < N_GRAPHS * HIDC) pooled[tid] = 0.f;
    if (tid < N_GRAPHS) cnt[tid] = 0.f;
}

// ---------------- conv1: node linears (2 -> 256) ----------------
__global__ void node_linear1(const float* __restrict__ x,
                             const float* __restrict__ Wq, const float* __restrict__ bq,
                             const float* __restrict__ Wk, const float* __restrict__ bk,
                             const float* __restrict__ Wv, const float* __restrict__ bv,
                             float* __restrict__ q1, float* __restrict__ k1,
                             float* __restrict__ v1) {
    int tid = blockIdx.x * 256 + threadIdx.x;   // N*256 threads
    int n = tid >> 8, d = tid & 255;
    float x0 = x[n * 2 + 0], x1 = x[n * 2 + 1];
    q1[tid] = x0 * Wq[d] + x1 * Wq[D1 + d] + bq[d];
    k1[tid] = x0 * Wk[d] + x1 * Wk[D1 + d] + bk[d];
    v1[tid] = x0 * Wv[d] + x1 * Wv[D1 + d] + bv[d];
}

// ---------------- conv1: alpha + segment max (one wave per edge*head) -------
__global__ void edge_alpha1(const int* __restrict__ ei, const float* __restrict__ ea,
                            const float* __restrict__ We, const float* __restrict__ q1,
                            const float* __restrict__ k1, float* __restrict__ alpha,
                            unsigned int* __restrict__ amax) {
    int edge = blockIdx.x;                     // one block per edge, 4 waves = 4 heads
    int head = threadIdx.x >> 6;
    int lane = threadIdx.x & 63;
    int src = ei[edge], dst = ei[N_EDGES + edge];
    const float* eaE = ea + (size_t)edge * EDIM;
    float ev = 0.f;
    #pragma unroll
    for (int j = 0; j < EDIM; ++j) ev += eaE[j] * We[j * D1 + head * 64 + lane];
    float kj = k1[(size_t)src * D1 + head * 64 + lane] + ev;
    float p  = q1[(size_t)dst * D1 + head * 64 + lane] * kj;
    p = wave_reduce_sum(p);
    if (lane == 0) {
        float a = p * 0.125f;                  // 1/sqrt(64)
        alpha[edge * NHEADS + head] = a;
        atomicMax(&amax[dst * NHEADS + head], enc_f(a));
    }
}

// ---------------- conv1: exp + denominator ----------------
__global__ void softmax_norm1(const int* __restrict__ ei, float* __restrict__ alpha,
                              const unsigned int* __restrict__ amax,
                              float* __restrict__ den) {
    int tid = blockIdx.x * 256 + threadIdx.x;  // E*4 threads (exact)
    int edge = tid >> 2, h = tid & 3;
    int dst = ei[N_EDGES + edge];
    float m = dec_f(amax[dst * NHEADS + h]);
    float ex = expf(alpha[tid] - m);
    alpha[tid] = ex;
    atomicAdd(&den[dst * NHEADS + h], ex);
}

// ---------------- conv1: weighted message scatter ----------------
__global__ void edge_msg1(const int* __restrict__ ei, const float* __restrict__ ea,
                          const float* __restrict__ We, const float* __restrict__ v1,
                          const float* __restrict__ alpha, const float* __restrict__ den,
                          float* __restrict__ out1) {
    int edge = blockIdx.x;
    int head = threadIdx.x >> 6;
    int lane = threadIdx.x & 63;
    int src = ei[edge], dst = ei[N_EDGES + edge];
    float w = alpha[edge * NHEADS + head] / (den[dst * NHEADS + head] + 1e-16f);
    const float* eaE = ea + (size_t)edge * EDIM;
    float ev = 0.f;
    #pragma unroll
    for (int j = 0; j < EDIM; ++j) ev += eaE[j] * We[j * D1 + head * 64 + lane];
    float m = (v1[(size_t)src * D1 + head * 64 + lane] + ev) * w;
    atomicAdd(&out1[(size_t)dst * D1 + head * 64 + lane], m);
}

// ---------------- conv1: beta-gated skip + relu (in place on out1) ----------
__global__ void beta_skip1(const float* __restrict__ x,
                           const float* __restrict__ Wskip, const float* __restrict__ bskip,
                           const float* __restrict__ Wbeta,
                           float* __restrict__ io) {
    __shared__ float red[4];
    int n = blockIdx.x;
    int d = threadIdx.x;
    float x0 = x[n * 2 + 0], x1 = x[n * 2 + 1];
    float xr = x0 * Wskip[d] + x1 * Wskip[D1 + d] + bskip[d];
    float o  = io[(size_t)n * D1 + d];
    float part = o * Wbeta[d] + xr * Wbeta[D1 + d] + (o - xr) * Wbeta[2 * D1 + d];
    part = wave_reduce_sum(part);
    int wid = threadIdx.x >> 6, lane = threadIdx.x & 63;
    if (lane == 0) red[wid] = part;
    __syncthreads();
    float tot = red[0] + red[1] + red[2] + red[3];
    float beta = 1.f / (1.f + expf(-tot));
    float h = beta * xr + (1.f - beta) * o;
    io[(size_t)n * D1 + d] = fmaxf(h, 0.f);
}

// ---------------- conv2: node linears (256 -> 64), 4 nodes/block -------------
__global__ void node_linear2(const float* __restrict__ h1,
                             const float* __restrict__ Wq, const float* __restrict__ bq,
                             const float* __restrict__ Wk, const float* __restrict__ bk,
                             const float* __restrict__ Wv, const float* __restrict__ bv,
                             const float* __restrict__ Ws, const float* __restrict__ bs,
                             float* __restrict__ q2, float* __restrict__ k2,
                             float* __restrict__ v2, float* __restrict__ xr2) {
    __shared__ float hb[4][D1];
    int nb = blockIdx.x * 4;
    int t = threadIdx.x;
    #pragma unroll
    for (int i = 0; i < 4; ++i) hb[i][t] = h1[(size_t)(nb + i) * D1 + t];
    __syncthreads();
    int m = t >> 6, d = t & 63;
    const float* W; const float* b; float* outp;
    if (m == 0)      { W = Wq; b = bq; outp = q2; }
    else if (m == 1) { W = Wk; b = bk; outp = k2; }
    else if (m == 2) { W = Wv; b = bv; outp = v2; }
    else             { W = Ws; b = bs; outp = xr2; }
    float a0 = b[d], a1 = b[d], a2 = b[d], a3 = b[d];
    for (int kk = 0; kk < D1; ++kk) {
        float w = W[kk * 64 + d];
        a0 += hb[0][kk] * w; a1 += hb[1][kk] * w;
        a2 += hb[2][kk] * w; a3 += hb[3][kk] * w;
    }
    outp[(size_t)(nb + 0) * 64 + d] = a0;
    outp[(size_t)(nb + 1) * 64 + d] = a1;
    outp[(size_t)(nb + 2) * 64 + d] = a2;
    outp[(size_t)(nb + 3) * 64 + d] = a3;
}

// ---------------- conv2: alpha + segment max (one wave per edge) -------------
__global__ void edge_alpha2(const int* __restrict__ ei, const float* __restrict__ ea,
                            const float* __restrict__ We, const float* __restrict__ q2,
                            const float* __restrict__ k2, float* __restrict__ alpha,
                            unsigned int* __restrict__ amax) {
    int wid = blockIdx.x * 4 + (threadIdx.x >> 6);   // E/4 blocks, exact
    int lane = threadIdx.x & 63;
    int src = ei[wid], dst = ei[N_EDGES + wid];
    const float* eaE = ea + (size_t)wid * EDIM;
    float ev = 0.f;
    #pragma unroll
    for (int j = 0; j < EDIM; ++j) ev += eaE[j] * We[j * 64 + lane];
    float kj = k2[(size_t)src * 64 + lane] + ev;
    float p  = q2[(size_t)dst * 64 + lane] * kj;
    p = wave_reduce_sum(p);
    if (lane == 0) {
        float a = p * 0.125f;
        alpha[wid] = a;
        atomicMax(&amax[dst], enc_f(a));
    }
}

__global__ void softmax_norm2(const int* __restrict__ ei, float* __restrict__ alpha,
                              const unsigned int* __restrict__ amax,
                              float* __restrict__ den) {
    int tid = blockIdx.x * 256 + threadIdx.x;
    if (tid >= N_EDGES) return;
    int dst = ei[N_EDGES + tid];
    float ex = expf(alpha[tid] - dec_f(amax[dst]));
    alpha[tid] = ex;
    atomicAdd(&den[dst], ex);
}

__global__ void edge_msg2(const int* __restrict__ ei, const float* __restrict__ ea,
                          const float* __restrict__ We, const float* __restrict__ v2,
                          const float* __restrict__ alpha, const float* __restrict__ den,
                          float* __restrict__ out2) {
    int wid = blockIdx.x * 4 + (threadIdx.x >> 6);
    int lane = threadIdx.x & 63;
    int src = ei[wid], dst = ei[N_EDGES + wid];
    float w = alpha[wid] / (den[dst] + 1e-16f);
    const float* eaE = ea + (size_t)wid * EDIM;
    float ev = 0.f;
    #pragma unroll
    for (int j = 0; j < EDIM; ++j) ev += eaE[j] * We[j * 64 + lane];
    float m = (v2[(size_t)src * 64 + lane] + ev) * w;
    atomicAdd(&out2[(size_t)dst * 64 + lane], m);
}

// ---------------- conv2: beta skip + relu + pool ----------------
__global__ void beta_pool2(const float* __restrict__ out2, const float* __restrict__ xr2,
                           const float* __restrict__ Wbeta,
                           const int* __restrict__ batch,
                           float* __restrict__ pooled, float* __restrict__ cnt) {
    int n = blockIdx.x * 4 + (threadIdx.x >> 6);   // N/4 blocks, exact
    int lane = threadIdx.x & 63;
    float o  = out2[(size_t)n * 64 + lane];
    float xr = xr2[(size_t)n * 64 + lane];
    float part = o * Wbeta[lane] + xr * Wbeta[64 + lane] + (o - xr) * Wbeta[128 + lane];
    part = wave_reduce_sum(part);
    float tot = __shfl(part, 0);
    float beta = 1.f / (1.f + expf(-tot));
    float h = fmaxf(beta * xr + (1.f - beta) * o, 0.f);
    int g = batch[n];
    atomicAdd(&pooled[g * 64 + lane], h);
    if (lane == 0) atomicAdd(&cnt[g], 1.0f);
}

// ---------------- final linear ----------------
__global__ void final_lin(const float* __restrict__ pooled, const float* __restrict__ cnt,
                          const float* __restrict__ Wlin, const float* __restrict__ blin,
                          float* __restrict__ out) {
    int t = threadIdx.x;
    if (t >= N_GRAPHS * OUTF) return;
    int g = t / OUTF, o = t % OUTF;
    float inv = 1.f / fmaxf(cnt[g], 1.f);
    float acc = 0.f;
    for (int kk = 0; kk < HIDC; ++kk) acc += pooled[g * 64 + kk] * Wlin[kk * OUTF + o];
    out[t] = acc * inv + blin[o];
}

extern "C" void kernel_launch(void* const* d_in, const int* in_sizes, int n_in,
                              void* d_out, int out_size, void* d_ws, size_t ws_size,
                              hipStream_t stream) {
    const float* x      = (const float*)d_in[0];
    const int*   ei     = (const int*)d_in[1];
    const float* ea     = (const float*)d_in[2];
    const int*   batch  = (const int*)d_in[3];
    const float* Wq1    = (const float*)d_in[4];  const float* bq1    = (const float*)d_in[5];
    const float* Wk1    = (const float*)d_in[6];  const float* bk1    = (const float*)d_in[7];
    const float* Wv1    = (const float*)d_in[8];  const float* bv1    = (const float*)d_in[9];
    const float* We1    = (const float*)d_in[10];
    const float* Wskip1 = (const float*)d_in[11]; const float* bskip1 = (const float*)d_in[12];
    const float* Wbeta1 = (const float*)d_in[13];
    const float* Wq2    = (const float*)d_in[14]; const float* bq2    = (const float*)d_in[15];
    const float* Wk2    = (const float*)d_in[16]; const float* bk2    = (const float*)d_in[17];
    const float* Wv2    = (const float*)d_in[18]; const float* bv2    = (const float*)d_in[19];
    const float* We2    = (const float*)d_in[20];
    const float* Wskip2 = (const float*)d_in[21]; const float* bskip2 = (const float*)d_in[22];
    const float* Wbeta2 = (const float*)d_in[23];
    const float* Wlin   = (const float*)d_in[24]; const float* blin   = (const float*)d_in[25];

    float* ws = (float*)d_ws;
    float* out1  = ws;                                   // N*256 (conv1 out, then h1)
    float* q1    = out1 + (size_t)N_NODES * D1;          // N*256
    float* k1    = q1   + (size_t)N_NODES * D1;          // N*256
    float* v1    = k1   + (size_t)N_NODES * D1;          // N*256
    float* alpha = v1   + (size_t)N_NODES * D1;          // E*4
    unsigned int* amax = (unsigned int*)(alpha + (size_t)N_EDGES * NHEADS);  // N*4
    float* den   = (float*)(amax + (size_t)N_NODES * NHEADS);                // N*4
    float* pooled = den + (size_t)N_NODES * NHEADS;      // G*64
    float* cnt    = pooled + N_GRAPHS * HIDC;            // G
    // conv2 aliases (conv1 q/k/v buffers are dead by then)
    float* q2   = q1;
    float* xr2  = q1 + (size_t)N_NODES * HIDC;
    float* k2   = k1;
    float* out2 = k1 + (size_t)N_NODES * HIDC;
    float* v2   = v1;
    unsigned int* amax2 = amax;   // first N entries
    float* den2 = den;            // first N entries

    // ---- conv1 ----
    init1_kernel<<<N_NODES, 256, 0, stream>>>(out1, den, amax);
    node_linear1<<<N_NODES, 256, 0, stream>>>(x, Wq1, bq1, Wk1, bk1, Wv1, bv1, q1, k1, v1);
    edge_alpha1<<<N_EDGES, 256, 0, stream>>>(ei, ea, We1, q1, k1, alpha, amax);
    softmax_norm1<<<(N_EDGES * NHEADS) / 256, 256, 0, stream>>>(ei, alpha, amax, den);
    edge_msg1<<<N_EDGES, 256, 0, stream>>>(ei, ea, We1, v1, alpha, den, out1);
    beta_skip1<<<N_NODES, 256, 0, stream>>>(x, Wskip1, bskip1, Wbeta1, out1);

    // ---- conv2 ----
    init2_kernel<<<(N_NODES * HIDC) / 256, 256, 0, stream>>>(out2, den2, amax2, pooled, cnt);
    node_linear2<<<N_NODES / 4, 256, 0, stream>>>(out1, Wq2, bq2, Wk2, bk2, Wv2, bv2,
                                                  Wskip2, bskip2, q2, k2, v2, xr2);
    edge_alpha2<<<N_EDGES / 4, 256, 0, stream>>>(ei, ea, We2, q2, k2, alpha, amax2);
    softmax_norm2<<<(N_EDGES + 255) / 256, 256, 0, stream>>>(ei, alpha, amax2, den2);
    edge_msg2<<<N_EDGES / 4, 256, 0, stream>>>(ei, ea, We2, v2, alpha, den2, out2);
    beta_pool2<<<N_NODES / 4, 256, 0, stream>>>(out2, xr2, Wbeta2, batch, pooled, cnt);
    final_lin<<<1, 256, 0, stream>>>(pooled, cnt, Wlin, blin, (float*)d_out);
}

// Round 2
// 874.078 us; speedup vs baseline: 1.8687x; 1.8687x over previous
//
#include <hip/hip_runtime.h>

#define N_NODES 40000
#define N_EDGES 400000
#define N_GRAPHS 64
#define D1 256      // heads*hid for conv1
#define HIDC 64
#define NHEADS 4
#define EDIM 18
#define OUTF 3

// ---------------- init: zero degree histogram + pool accumulators ----------
__global__ void init_kernel(int* __restrict__ deg, float* __restrict__ pooled,
                            float* __restrict__ cnt) {
    int t = blockIdx.x * 256 + threadIdx.x;
    if (t < N_NODES) deg[t] = 0;
    if (t < N_GRAPHS * HIDC) pooled[t] = 0.f;
    if (t < N_GRAPHS) cnt[t] = 0.f;
}

// ---------------- conv1 low-rank precompute ----------------
// cbuf layout per head h (63 floats at h*63):
//   [0..9)  M[a*3+b] = A_a(h) . B_b(h)   (A = {Wq row0, Wq row1, bq}, B = {Wk row0, Wk row1, bk})
//   [9..63) U[r*18+j] = A_r(h) . We1[j] (h-slice)
__global__ void precompute1(const float* __restrict__ Wq, const float* __restrict__ bq,
                            const float* __restrict__ Wk, const float* __restrict__ bk,
                            const float* __restrict__ We, float* __restrict__ cbuf) {
    int t = threadIdx.x;
    if (t < 36) {
        int h = t / 9, r = t % 9, a = r / 3, b = r % 3;
        const float* A = (a == 0) ? Wq : (a == 1) ? Wq + D1 : bq;
        const float* B = (b == 0) ? Wk : (b == 1) ? Wk + D1 : bk;
        float s = 0.f;
        for (int c = 0; c < 64; ++c) s += A[h * 64 + c] * B[h * 64 + c];
        cbuf[h * 63 + a * 3 + b] = s;
    } else if (t < 252) {
        int i = t - 36;
        int h = i / 54, rr = (i % 54) / 18, j = i % 18;
        const float* A = (rr == 0) ? Wq : (rr == 1) ? Wq + D1 : bq;
        float s = 0.f;
        for (int c = 0; c < 64; ++c) s += A[h * 64 + c] * We[j * D1 + h * 64 + c];
        cbuf[h * 63 + 9 + rr * 18 + j] = s;
    }
}

// ---------------- CSR build ----------------
__global__ void hist_kernel(const int* __restrict__ ei, int* __restrict__ deg) {
    int e = blockIdx.x * 256 + threadIdx.x;
    if (e < N_EDGES) atomicAdd(&deg[ei[N_EDGES + e]], 1);
}

__global__ void scan_kernel(const int* __restrict__ deg, int* __restrict__ row_ptr,
                            int* __restrict__ cursor) {
    __shared__ int sums[1024];
    int t = threadIdx.x;
    const int PER = 40;                      // 1024*40 >= 40000
    int base = t * PER;
    int s = 0;
    for (int i = 0; i < PER; ++i) {
        int idx = base + i;
        if (idx < N_NODES) s += deg[idx];
    }
    sums[t] = s;
    __syncthreads();
    for (int off = 1; off < 1024; off <<= 1) {
        int v = sums[t];
        int w = (t >= off) ? sums[t - off] : 0;
        __syncthreads();
        sums[t] = v + w;
        __syncthreads();
    }
    int run = (t == 0) ? 0 : sums[t - 1];
    for (int i = 0; i < PER; ++i) {
        int idx = base + i;
        if (idx < N_NODES) {
            row_ptr[idx] = run;
            cursor[idx] = run;
            run += deg[idx];
        }
    }
    if (t == 0) row_ptr[N_NODES] = sums[1023];
}

__global__ void scatter_kernel(const int* __restrict__ ei, const float* __restrict__ ea,
                               const float* __restrict__ x, int* __restrict__ cursor,
                               int* __restrict__ src_s, float* __restrict__ ea_s,
                               float2* __restrict__ x_s) {
    int e = blockIdx.x * 256 + threadIdx.x;
    if (e >= N_EDGES) return;
    int src = ei[e], dst = ei[N_EDGES + e];
    int p = atomicAdd(&cursor[dst], 1);
    src_s[p] = src;
    x_s[p] = make_float2(x[src * 2], x[src * 2 + 1]);
    const float* srow = ea + (size_t)e * EDIM;
    float* drow = ea_s + (size_t)p * EDIM;
    #pragma unroll
    for (int j = 0; j < EDIM; ++j) drow[j] = srow[j];
}

// ---------------- conv1 fused: one thread per (node, head) ----------------
// Online softmax over incident edges; accumulates s0=sum(w~ x0s), s1=sum(w~ x1s),
// l=sum(w~), sea[j]=sum(w~ ea[j]) with running-max rescale. 65 FLOP/edge.
__global__ void conv1_fused(const float* __restrict__ x, const int* __restrict__ row_ptr,
                            const float* __restrict__ ea_s, const float2* __restrict__ x_s,
                            const float* __restrict__ cbuf, float* __restrict__ acc1) {
    __shared__ float cb[252];
    int t = threadIdx.x;
    if (t < 252) cb[t] = cbuf[t];
    __syncthreads();
    int tid = blockIdx.x * 256 + t;          // exactly N*4 threads
    int node = tid >> 2, h = tid & 3;
    const float* c = &cb[h * 63];
    float x0 = x[node * 2], x1 = x[node * 2 + 1];
    // coef_b = sum_a xa_d * M[a][b]  (x2_d = 1)
    float c0 = x0 * c[0] + x1 * c[3] + c[6];
    float c1 = x0 * c[1] + x1 * c[4] + c[7];
    float c2 = x0 * c[2] + x1 * c[5] + c[8];
    float u[EDIM];
    #pragma unroll
    for (int j = 0; j < EDIM; ++j) u[j] = x0 * c[9 + j] + x1 * c[27 + j] + c[45 + j];

    float m = -INFINITY, l = 0.f, s0 = 0.f, s1 = 0.f;
    float sea[EDIM];
    #pragma unroll
    for (int j = 0; j < EDIM; ++j) sea[j] = 0.f;

    int beg = row_ptr[node], end = row_ptr[node + 1];
    for (int p = beg; p < end; ++p) {
        float2 xs = x_s[p];
        const float* ear = ea_s + (size_t)p * EDIM;
        float ev[EDIM];
        float a = c0 * xs.x + c1 * xs.y + c2;
        #pragma unroll
        for (int j = 0; j < EDIM; ++j) { ev[j] = ear[j]; a += ev[j] * u[j]; }
        a *= 0.125f;                          // 1/sqrt(64)
        float mn = fmaxf(m, a);
        float f  = __expf(m - mn);            // m=-inf first iter -> 0
        float ex = __expf(a - mn);
        l  = l  * f + ex;
        s0 = s0 * f + ex * xs.x;
        s1 = s1 * f + ex * xs.y;
        #pragma unroll
        for (int j = 0; j < EDIM; ++j) sea[j] = sea[j] * f + ex * ev[j];
        m = mn;
    }
    float* o = acc1 + (size_t)tid * 21;
    o[0] = s0; o[1] = s1; o[2] = l;
    #pragma unroll
    for (int j = 0; j < EDIM; ++j) o[3 + j] = sea[j];
}

// ---------------- conv1 finalize: expand accumulators, beta skip, relu ------
__global__ void finalize1(const float* __restrict__ x, const float* __restrict__ acc1,
                          const float* __restrict__ Wv, const float* __restrict__ bv,
                          const float* __restrict__ We, const float* __restrict__ Wskip,
                          const float* __restrict__ bskip, const float* __restrict__ Wbeta,
                          float* __restrict__ h1) {
    __shared__ float red[4];
    int node = blockIdx.x;
    int t = threadIdx.x;                      // = d in [0,256)
    int h = t >> 6;
    const float* a = acc1 + (size_t)(node * 4 + h) * 21;
    float s0 = a[0], s1 = a[1], l = a[2];
    float o = s0 * Wv[t] + s1 * Wv[D1 + t] + l * bv[t];
    #pragma unroll
    for (int j = 0; j < EDIM; ++j) o += a[3 + j] * We[j * D1 + t];
    o /= (l + 1e-16f);
    float x0 = x[node * 2], x1 = x[node * 2 + 1];
    float xr = x0 * Wskip[t] + x1 * Wskip[D1 + t] + bskip[t];
    float part = o * Wbeta[t] + xr * Wbeta[D1 + t] + (o - xr) * Wbeta[2 * D1 + t];
    #pragma unroll
    for (int off = 32; off; off >>= 1) part += __shfl_xor(part, off);
    if ((t & 63) == 0) red[t >> 6] = part;
    __syncthreads();
    float tot = red[0] + red[1] + red[2] + red[3];
    float beta = 1.f / (1.f + __expf(-tot));
    h1[(size_t)node * D1 + t] = fmaxf(beta * xr + (1.f - beta) * o, 0.f);
}

// ---------------- conv2: node linears (256 -> 64 x4), 4 nodes/block ---------
__global__ void node_linear2(const float* __restrict__ h1,
                             const float* __restrict__ Wq, const float* __restrict__ bq,
                             const float* __restrict__ Wk, const float* __restrict__ bk,
                             const float* __restrict__ Wv, const float* __restrict__ bv,
                             const float* __restrict__ Ws, const float* __restrict__ bs,
                             float* __restrict__ q2, float* __restrict__ k2,
                             float* __restrict__ v2, float* __restrict__ xr2) {
    __shared__ float hb[4][D1];
    int nb = blockIdx.x * 4;
    int t = threadIdx.x;
    #pragma unroll
    for (int i = 0; i < 4; ++i) hb[i][t] = h1[(size_t)(nb + i) * D1 + t];
    __syncthreads();
    int m = t >> 6, d = t & 63;
    const float* W; const float* b; float* outp;
    if (m == 0)      { W = Wq; b = bq; outp = q2; }
    else if (m == 1) { W = Wk; b = bk; outp = k2; }
    else if (m == 2) { W = Wv; b = bv; outp = v2; }
    else             { W = Ws; b = bs; outp = xr2; }
    float a0 = b[d], a1 = b[d], a2 = b[d], a3 = b[d];
    for (int kk = 0; kk < D1; ++kk) {
        float w = W[kk * 64 + d];
        a0 += hb[0][kk] * w; a1 += hb[1][kk] * w;
        a2 += hb[2][kk] * w; a3 += hb[3][kk] * w;
    }
    outp[(size_t)(nb + 0) * 64 + d] = a0;
    outp[(size_t)(nb + 1) * 64 + d] = a1;
    outp[(size_t)(nb + 2) * 64 + d] = a2;
    outp[(size_t)(nb + 3) * 64 + d] = a3;
}

// ---------------- conv2 fused: wave per node — attn + beta + pool -----------
__global__ void conv2_fused(const int* __restrict__ row_ptr, const int* __restrict__ src_s,
                            const float* __restrict__ ea_s, const float* __restrict__ q2,
                            const float* __restrict__ k2, const float* __restrict__ v2,
                            const float* __restrict__ xr2, const float* __restrict__ We2,
                            const float* __restrict__ Wb2, const int* __restrict__ batch,
                            float* __restrict__ pooled, float* __restrict__ cnt) {
    __shared__ float w2[EDIM * 64];
    int t = threadIdx.x;
    for (int i = t; i < EDIM * 64; i += 256) w2[i] = We2[i];
    __syncthreads();
    int node = blockIdx.x * 4 + (t >> 6);     // exactly N nodes
    int lane = t & 63;
    float q = q2[(size_t)node * 64 + lane];
    float m = -INFINITY, l = 0.f, acc = 0.f;
    int beg = row_ptr[node], end = row_ptr[node + 1];
    for (int p = beg; p < end; ++p) {
        int src = src_s[p];
        const float* ear = ea_s + (size_t)p * EDIM;
        float e = 0.f;
        #pragma unroll
        for (int j = 0; j < EDIM; ++j) e += ear[j] * w2[j * 64 + lane];
        float kj = k2[(size_t)src * 64 + lane] + e;
        float d = q * kj;
        #pragma unroll
        for (int off = 32; off; off >>= 1) d += __shfl_xor(d, off);
        float a = d * 0.125f;
        float mn = fmaxf(m, a);
        float f  = __expf(m - mn);
        float ex = __expf(a - mn);
        l   = l   * f + ex;
        acc = acc * f + ex * (v2[(size_t)src * 64 + lane] + e);
        m = mn;
    }
    float o = acc / (l + 1e-16f);
    float xr = xr2[(size_t)node * 64 + lane];
    float part = o * Wb2[lane] + xr * Wb2[64 + lane] + (o - xr) * Wb2[128 + lane];
    #pragma unroll
    for (int off = 32; off; off >>= 1) part += __shfl_xor(part, off);
    float beta = 1.f / (1.f + __expf(-part));
    float hh = fmaxf(beta * xr + (1.f - beta) * o, 0.f);
    int g = batch[node];
    atomicAdd(&pooled[g * 64 + lane], hh);
    if (lane == 0) atomicAdd(&cnt[g], 1.f);
}

// ---------------- final linear ----------------
__global__ void final_lin(const float* __restrict__ pooled, const float* __restrict__ cnt,
                          const float* __restrict__ Wlin, const float* __restrict__ blin,
                          float* __restrict__ out) {
    int t = threadIdx.x;
    if (t >= N_GRAPHS * OUTF) return;
    int g = t / OUTF, o = t % OUTF;
    float inv = 1.f / fmaxf(cnt[g], 1.f);
    float acc = 0.f;
    for (int kk = 0; kk < HIDC; ++kk) acc += pooled[g * 64 + kk] * Wlin[kk * OUTF + o];
    out[t] = acc * inv + blin[o];
}

extern "C" void kernel_launch(void* const* d_in, const int* in_sizes, int n_in,
                              void* d_out, int out_size, void* d_ws, size_t ws_size,
                              hipStream_t stream) {
    const float* x      = (const float*)d_in[0];
    const int*   ei     = (const int*)d_in[1];
    const float* ea     = (const float*)d_in[2];
    const int*   batch  = (const int*)d_in[3];
    const float* Wq1    = (const float*)d_in[4];  const float* bq1    = (const float*)d_in[5];
    const float* Wk1    = (const float*)d_in[6];  const float* bk1    = (const float*)d_in[7];
    const float* Wv1    = (const float*)d_in[8];  const float* bv1    = (const float*)d_in[9];
    const float* We1    = (const float*)d_in[10];
    const float* Wskip1 = (const float*)d_in[11]; const float* bskip1 = (const float*)d_in[12];
    const float* Wbeta1 = (const float*)d_in[13];
    const float* Wq2    = (const float*)d_in[14]; const float* bq2    = (const float*)d_in[15];
    const float* Wk2    = (const float*)d_in[16]; const float* bk2    = (const float*)d_in[17];
    const float* Wv2    = (const float*)d_in[18]; const float* bv2    = (const float*)d_in[19];
    const float* We2    = (const float*)d_in[20];
    const float* Wskip2 = (const float*)d_in[21]; const float* bskip2 = (const float*)d_in[22];
    const float* Wbeta2 = (const float*)d_in[23];
    const float* Wlin   = (const float*)d_in[24]; const float* blin   = (const float*)d_in[25];

    float* f = (float*)d_ws;
    float* h1     = f;                                     // N*256
    float* q2     = h1 + (size_t)N_NODES * D1;             // N*64
    float* k2     = q2 + (size_t)N_NODES * HIDC;
    float* v2     = k2 + (size_t)N_NODES * HIDC;
    float* xr2    = v2 + (size_t)N_NODES * HIDC;
    float* acc1   = xr2 + (size_t)N_NODES * HIDC;          // N*4*21
    float* ea_s   = acc1 + (size_t)N_NODES * 4 * 21;       // E*18
    float* x_sf   = ea_s + (size_t)N_EDGES * EDIM;         // E*2 (float2)
    float* pooled = x_sf + (size_t)N_EDGES * 2;            // G*64
    float* cnt    = pooled + N_GRAPHS * HIDC;              // G
    float* cbuf   = cnt + N_GRAPHS;                        // 252
    int* deg      = (int*)(cbuf + 252);                    // N
    int* row_ptr  = deg + N_NODES;                         // N+1
    int* cursor   = row_ptr + N_NODES + 1;                 // N
    int* src_s    = cursor + N_NODES;                      // E
    float2* x_s   = (float2*)x_sf;

    const int EB = (N_EDGES + 255) / 256;
    const int NB = (N_NODES + 255) / 256;

    init_kernel<<<NB, 256, 0, stream>>>(deg, pooled, cnt);
    precompute1<<<1, 256, 0, stream>>>(Wq1, bq1, Wk1, bk1, We1, cbuf);
    hist_kernel<<<EB, 256, 0, stream>>>(ei, deg);
    scan_kernel<<<1, 1024, 0, stream>>>(deg, row_ptr, cursor);
    scatter_kernel<<<EB, 256, 0, stream>>>(ei, ea, x, cursor, src_s, ea_s, x_s);

    conv1_fused<<<(N_NODES * 4) / 256, 256, 0, stream>>>(x, row_ptr, ea_s, x_s, cbuf, acc1);
    finalize1<<<N_NODES, 256, 0, stream>>>(x, acc1, Wv1, bv1, We1, Wskip1, bskip1, Wbeta1, h1);

    node_linear2<<<N_NODES / 4, 256, 0, stream>>>(h1, Wq2, bq2, Wk2, bk2, Wv2, bv2,
                                                  Wskip2, bskip2, q2, k2, v2, xr2);
    conv2_fused<<<N_NODES / 4, 256, 0, stream>>>(row_ptr, src_s, ea_s, q2, k2, v2, xr2,
                                                 We2, Wbeta2, batch, pooled, cnt);
    final_lin<<<1, 256, 0, stream>>>(pooled, cnt, Wlin, blin, (float*)d_out);
}